// Round 2
// baseline (729.299 us; speedup 1.0000x reference)
//
#include <hip/hip_runtime.h>
#include <hip/hip_fp16.h>
#include <hip/hip_cooperative_groups.h>
#include <math.h>

namespace cg = cooperative_groups;

namespace {
constexpr int kH = 384, kW = 384, kBn = 2;
constexpr int kHW = kH * kW;       // 147456
constexpr int kOMD = 112;
constexpr int kNB = kBn * (kHW / 64);   // 4608 tiles
constexpr int kNB8 = kNB / 8;           // 576 per XCD
constexpr int kGrid = 1536;             // 6 blocks/CU, 4608/1536 = 3 tiles exactly
}

__device__ __forceinline__ int swz(int t) {
    // XCD-aware: block bid -> XCD bid%8; each XCD owns a contiguous tile range.
    return (t & 7) * kNB8 + (t >> 3);
}

__device__ __forceinline__ unsigned pack2h(float a, float b) {
    unsigned short lo = __builtin_bit_cast(unsigned short, __float2half_rn(a));
    unsigned short hi = __builtin_bit_cast(unsigned short, __float2half_rn(b));
    return (unsigned)lo | ((unsigned)hi << 16);
}

// fp16 pair fma: acc += wgt * half2(u)  -> compiler forms v_fma_mix_f32
__device__ __forceinline__ void fma2h(float& a0, float& a1, float w, unsigned u) {
    __half2 h = __builtin_bit_cast(__half2, u);
    a0 = fmaf(w, __half2float(h.x), a0);
    a1 = fmaf(w, __half2float(h.y), a1);
}

// ---------------- phase 1: value[b][g][yx][c16] (fp16) = inp @ Wv + bv ----------------
__device__ __forceinline__ void phase_value(
        const float* __restrict__ inp, const float* __restrict__ Wv,
        const float* __restrict__ bv, unsigned short* __restrict__ value,
        float (*lds1)[68]) {
    const int tid = threadIdx.x;
    const int p = tid & 63;
    const int gs = __builtin_amdgcn_readfirstlane(tid >> 6);   // wave-uniform

    for (int t = blockIdx.x; t < kNB; t += gridDim.x) {
        const int bid = swz(t);
        const int b = bid / (kHW / 64);
        const int pix0 = (bid % (kHW / 64)) * 64;
        const float* ib = inp + (size_t)b * 64 * kHW + pix0;

        __syncthreads();   // prev tile's lds1 reads done before overwrite
        // stage inp transposed: lds1[c][p], float4 loads (rows contiguous 256B)
        for (int i = tid; i < 1024; i += 256) {
            const int c = i >> 4, p4 = (i & 15) << 2;
            const float4 v = *(const float4*)(ib + (size_t)c * kHW + p4);
            *(float4*)&lds1[c][p4] = v;
        }
        __syncthreads();

        float acc[16];
        {
            const float* bg = bv + gs * 16;            // wave-uniform -> s_load
            #pragma unroll
            for (int j = 0; j < 16; ++j) acc[j] = bg[j];
        }
        #pragma unroll 4
        for (int ci = 0; ci < 64; ++ci) {
            const float a = lds1[ci][p];               // 1 ds_read_b32 / ci
            const float* wr = Wv + ci * 64 + gs * 16;  // wave-uniform -> s_load
            #pragma unroll
            for (int j = 0; j < 16; ++j) acc[j] = fmaf(a, wr[j], acc[j]);
        }

        unsigned u[8];
        #pragma unroll
        for (int j = 0; j < 8; ++j) u[j] = pack2h(acc[2 * j], acc[2 * j + 1]);
        uint4* vo = (uint4*)(value + ((size_t)(b * 4 + gs) * kHW + pix0 + p) * 16);
        vo[0] = make_uint4(u[0], u[1], u[2], u[3]);
        vo[1] = make_uint4(u[4], u[5], u[6], u[7]);
    }
}

// ---------------- phase 2: dw conv -> om -> deformable sampling -> @Wo -> out ----------------
__device__ __forceinline__ void phase_main(
        const float* __restrict__ inp, const float* __restrict__ Wdw,
        const float* __restrict__ bdw, const float* __restrict__ Wom,
        const float* __restrict__ bom, const float* __restrict__ Wo,
        const unsigned short* __restrict__ value, float* __restrict__ out,
        float (*lds1)[68]) {
    const int tid = threadIdx.x;
    const int p = tid & 63;
    const int gs = __builtin_amdgcn_readfirstlane(tid >> 6);   // wave-uniform

    for (int t = blockIdx.x; t < kNB; t += gridDim.x) {
        const int bid = swz(t);
        const int b = bid / (kH * (kW / 64));
        const int rem = bid % (kH * (kW / 64));
        const int h = rem / (kW / 64);
        const int w0 = (rem % (kW / 64)) * 64;

        __syncthreads();   // prev tile's stage-D lds1 reads done

        // ---- stage A: depthwise 3x3 conv (zero pad) -> lds1[c][p] ----
        {
            const int w = w0 + p;
            #pragma unroll 4
            for (int cc = 0; cc < 16; ++cc) {
                const int c = gs * 16 + cc;             // wave-uniform
                const float* ib = inp + (size_t)(b * 64 + c) * kHW;
                float s = bdw[c];
                #pragma unroll
                for (int r = 0; r < 3; ++r) {
                    const int y = h - 1 + r;
                    if (y >= 0 && y < kH) {
                        const float* rowp = ib + (size_t)y * kW;
                        #pragma unroll
                        for (int kx = 0; kx < 3; ++kx) {
                            const int x = w - 1 + kx;
                            const float v = (x >= 0 && x < kW) ? rowp[x] : 0.f;
                            s = fmaf(v, Wdw[c * 9 + r * 3 + kx], s);
                        }
                    }
                }
                lds1[c][p] = s;
            }
        }
        __syncthreads();

        // ---- stage B: om[27] for (pixel p, group g), in registers ----
        float om[27];
        {
            const float* bg = bom + gs * 27;            // scalar loads
            #pragma unroll
            for (int j = 0; j < 27; ++j) om[j] = bg[j];
            #pragma unroll 4
            for (int ci = 0; ci < 64; ++ci) {
                const float a = lds1[ci][p];
                const float* wr = Wom + ci * kOMD + gs * 27;  // wave-uniform
                #pragma unroll
                for (int j = 0; j < 27; ++j) om[j] = fmaf(a, wr[j], om[j]);
            }
        }
        __syncthreads();   // lds1 reads done; stage C overwrites

        // ---- stage C: deformable bilinear sampling (fp16 value, v_fma_mix) ----
        {
            float acc[16];
            #pragma unroll
            for (int j = 0; j < 16; ++j) acc[j] = 0.f;
            const float fw = (float)(w0 + p);
            const float fh = (float)h;
            const unsigned short* vbase = value + (size_t)(b * 4 + gs) * kHW * 16;
            #pragma unroll
            for (int k = 0; k < 9; ++k) {
                const int ky = k / 3, kx = k % 3;
                const float dx = om[2 * k];
                const float dy = om[2 * k + 1];
                const float m = om[18 + k];
                const float px = fw + (float)(kx - 1) + dx;
                const float py = fh + (float)(ky - 1) + dy;
                const float x0f = floorf(px), y0f = floorf(py);
                const int x0 = (int)x0f, y0 = (int)y0f;
                const float wx1 = px - x0f, wy1 = py - y0f;
                const float wx0 = 1.f - wx1, wy0 = 1.f - wy1;
                #pragma unroll
                for (int cor = 0; cor < 4; ++cor) {
                    const int dy2 = cor >> 1, dx2 = cor & 1;
                    const int xi = x0 + dx2, yi = y0 + dy2;
                    float wgt = (dy2 ? wy1 : wy0) * (dx2 ? wx1 : wx0) * m;
                    if (xi < 0 || xi >= kW || yi < 0 || yi >= kH) wgt = 0.f;
                    const int xc = min(max(xi, 0), kW - 1);
                    const int yc = min(max(yi, 0), kH - 1);
                    const uint4* vp = (const uint4*)(vbase +
                            ((size_t)yc * kW + xc) * 16);
                    const uint4 u0 = vp[0];
                    const uint4 u1 = vp[1];
                    fma2h(acc[0],  acc[1],  wgt, u0.x);
                    fma2h(acc[2],  acc[3],  wgt, u0.y);
                    fma2h(acc[4],  acc[5],  wgt, u0.z);
                    fma2h(acc[6],  acc[7],  wgt, u0.w);
                    fma2h(acc[8],  acc[9],  wgt, u1.x);
                    fma2h(acc[10], acc[11], wgt, u1.y);
                    fma2h(acc[12], acc[13], wgt, u1.z);
                    fma2h(acc[14], acc[15], wgt, u1.w);
                }
            }
            // write sampled result transposed into lds1 (dw is dead now)
            #pragma unroll
            for (int j = 0; j < 16; ++j) lds1[gs * 16 + j][p] = acc[j];
        }
        __syncthreads();

        // ---- stage D: final @Wo, coalesced (B,C,H,W) writeout ----
        {
            float acc[16];
            #pragma unroll
            for (int j = 0; j < 16; ++j) acc[j] = 0.f;
            #pragma unroll 4
            for (int ci = 0; ci < 64; ++ci) {
                const float a = lds1[ci][p];
                const float* wr = Wo + ci * 64 + gs * 16;   // wave-uniform
                #pragma unroll
                for (int j = 0; j < 16; ++j) acc[j] = fmaf(a, wr[j], acc[j]);
            }
            float* ob = out + (size_t)(b * 64 + gs * 16) * kHW + (size_t)h * kW + w0 + p;
            #pragma unroll
            for (int j = 0; j < 16; ++j) ob[(size_t)j * kHW] = acc[j];
        }
    }
}

// ---------------- fused cooperative kernel ----------------
__global__ __launch_bounds__(256, 6) void k_fused(
        const float* __restrict__ inp, const float* __restrict__ Wv,
        const float* __restrict__ bv, const float* __restrict__ Wdw,
        const float* __restrict__ bdw, const float* __restrict__ Wom,
        const float* __restrict__ bom, const float* __restrict__ Wo,
        unsigned short* __restrict__ value, float* __restrict__ out) {
    __shared__ float lds1[64][68];
    phase_value(inp, Wv, bv, value, lds1);
    __threadfence();                 // release value writes to device scope
    cg::this_grid().sync();          // all phase-1 writes visible to all XCDs
    phase_main(inp, Wdw, bdw, Wom, bom, Wo, value, out, lds1);
}

// ---------------- non-cooperative fallback ----------------
__global__ __launch_bounds__(256) void k_p1(
        const float* __restrict__ inp, const float* __restrict__ Wv,
        const float* __restrict__ bv, unsigned short* __restrict__ value) {
    __shared__ float lds1[64][68];
    phase_value(inp, Wv, bv, value, lds1);
}

__global__ __launch_bounds__(256) void k_p2(
        const float* __restrict__ inp, const float* __restrict__ Wdw,
        const float* __restrict__ bdw, const float* __restrict__ Wom,
        const float* __restrict__ bom, const float* __restrict__ Wo,
        const unsigned short* __restrict__ value, float* __restrict__ out) {
    __shared__ float lds1[64][68];
    phase_main(inp, Wdw, bdw, Wom, bom, Wo, value, out, lds1);
}

extern "C" void kernel_launch(void* const* d_in, const int* in_sizes, int n_in,
                              void* d_out, int out_size, void* d_ws, size_t ws_size,
                              hipStream_t stream) {
    const float* inp = (const float*)d_in[0];
    const float* Wv  = (const float*)d_in[1];
    const float* bv  = (const float*)d_in[2];
    const float* Wdw = (const float*)d_in[3];
    const float* bdw = (const float*)d_in[4];
    const float* Wom = (const float*)d_in[5];
    const float* bom = (const float*)d_in[6];
    const float* Wo  = (const float*)d_in[7];
    float* outp = (float*)d_out;
    unsigned short* value = (unsigned short*)d_ws;   // [b][g][yx][16] fp16 = 37.7 MB

    void* args[] = {(void*)&inp, (void*)&Wv, (void*)&bv, (void*)&Wdw, (void*)&bdw,
                    (void*)&Wom, (void*)&bom, (void*)&Wo, (void*)&value, (void*)&outp};
    hipError_t err = hipLaunchCooperativeKernel((void*)k_fused, dim3(kGrid), dim3(256),
                                                args, 0, stream);
    if (err != hipSuccess) {
        // fallback: two classic launches (kernel boundary = the global sync)
        k_p1<<<kNB, 256, 0, stream>>>(inp, Wv, bv, value);
        k_p2<<<kNB, 256, 0, stream>>>(inp, Wdw, bdw, Wom, bom, Wo, value, outp);
    }
}

// Round 3
// 304.831 us; speedup vs baseline: 2.3925x; 2.3925x over previous
//
#include <hip/hip_runtime.h>
#include <hip/hip_fp16.h>
#include <math.h>

namespace {
constexpr int kH = 384, kW = 384, kBn = 2;
constexpr int kHW = kH * kW;       // 147456
constexpr int kOMD = 112;
constexpr int kNB = kBn * (kHW / 64);   // 4608 blocks
constexpr int kNB8 = kNB / 8;           // 576 per XCD
}

typedef _Float16 h2 __attribute__((ext_vector_type(2)));

// half2-packed channel-pair weights, prepped once by k_value block 0
__device__ unsigned g_Wom2[32 * kOMD];   // [ci2][j] = (Wom[2ci2][j], Wom[2ci2+1][j])
__device__ unsigned g_Wo2[32 * 64];      // [ci2][co] = (Wo[2ci2][co], Wo[2ci2+1][co])

__device__ __forceinline__ int swz(int t) {
    // XCD-aware: round-robin dispatch -> each XCD gets a contiguous range
    return (t & 7) * kNB8 + (t >> 3);
}

__device__ __forceinline__ unsigned pack2h(float a, float b) {
    unsigned short lo = __builtin_bit_cast(unsigned short, __float2half_rn(a));
    unsigned short hi = __builtin_bit_cast(unsigned short, __float2half_rn(b));
    return (unsigned)lo | ((unsigned)hi << 16);
}

#if __has_builtin(__builtin_amdgcn_fdot2)
__device__ __forceinline__ float dot2(unsigned a, unsigned b, float c) {
    return __builtin_amdgcn_fdot2(__builtin_bit_cast(h2, a),
                                  __builtin_bit_cast(h2, b), c, false);
}
#else
__device__ __forceinline__ float dot2(unsigned a, unsigned b, float c) {
    h2 ha = __builtin_bit_cast(h2, a), hb = __builtin_bit_cast(h2, b);
    c = fmaf((float)ha.x, (float)hb.x, c);
    c = fmaf((float)ha.y, (float)hb.y, c);
    return c;
}
#endif

// fp16 pair fma: acc += wgt * half2(u)  -> compiler forms v_fma_mix_f32
__device__ __forceinline__ void fma2h(float& a0, float& a1, float w, unsigned u) {
    __half2 h = __builtin_bit_cast(__half2, u);
    a0 = fmaf(w, __half2float(h.x), a0);
    a1 = fmaf(w, __half2float(h.y), a1);
}

// K1: value[b][g][yx][c16] (fp16) = inp(b,:,yx) @ Wv + bv
// wave g owns out-channels g*16..g*16+15; weights via wave-uniform s_loads;
// activations transposed in LDS, one ds_read_b32 per ci per thread.
// Block 0 additionally packs Wom/Wo into half2-pair device globals.
__global__ __launch_bounds__(256) void k_value(
        const float* __restrict__ inp, const float* __restrict__ Wv,
        const float* __restrict__ bv, const float* __restrict__ Wom,
        const float* __restrict__ Wo, unsigned short* __restrict__ value) {
    __shared__ float xin[64][64];   // [ci][p]; 2-way bank alias = free
    const int tid = threadIdx.x;

    if (blockIdx.x == 0) {          // one-time weight prep (idempotent)
        for (int i = tid; i < 32 * kOMD; i += 256) {
            const int ci2 = i / kOMD, j = i % kOMD;
            g_Wom2[i] = pack2h(Wom[(2 * ci2) * kOMD + j],
                               Wom[(2 * ci2 + 1) * kOMD + j]);
        }
        for (int i = tid; i < 32 * 64; i += 256) {
            const int ci2 = i >> 6, j = i & 63;
            g_Wo2[i] = pack2h(Wo[(2 * ci2) * 64 + j],
                              Wo[(2 * ci2 + 1) * 64 + j]);
        }
    }

    const int bid = swz(blockIdx.x);
    const int b = bid / (kHW / 64);
    const int pix0 = (bid % (kHW / 64)) * 64;
    const float* ib = inp + (size_t)b * 64 * kHW + pix0;
    for (int i = tid; i < 1024; i += 256) {
        const int c = i >> 4, p4 = (i & 15) << 2;
        const float4 v = *(const float4*)(ib + (size_t)c * kHW + p4);
        *(float4*)&xin[c][p4] = v;
    }
    __syncthreads();

    const int p = tid & 63;
    const int gs = __builtin_amdgcn_readfirstlane(tid >> 6);  // wave-uniform

    float acc[16];
    {
        const float* bg = bv + gs * 16;            // wave-uniform -> s_load
        #pragma unroll
        for (int j = 0; j < 16; ++j) acc[j] = bg[j];
    }
    #pragma unroll 4
    for (int ci = 0; ci < 64; ++ci) {
        const float a = xin[ci][p];                // 1 ds_read_b32 / ci
        const float* wr = Wv + ci * 64 + gs * 16;  // wave-uniform -> s_load
        #pragma unroll
        for (int j = 0; j < 16; ++j) acc[j] = fmaf(a, wr[j], acc[j]);
    }

    unsigned u[8];
    #pragma unroll
    for (int j = 0; j < 8; ++j) u[j] = pack2h(acc[2 * j], acc[2 * j + 1]);
    uint4* vo = (uint4*)(value + ((size_t)(b * 4 + gs) * kHW + pix0 + p) * 16);
    vo[0] = make_uint4(u[0], u[1], u[2], u[3]);
    vo[1] = make_uint4(u[4], u[5], u[6], u[7]);
}

// K2: fused depthwise conv -> om matvec (fdot2) -> deformable sampling -> @Wo (fdot2)
// One block = 64 consecutive pixels of one row. 256 threads.
__global__ __launch_bounds__(256) void k_main(
        const float* __restrict__ inp, const float* __restrict__ Wdw,
        const float* __restrict__ bdw, const float* __restrict__ bom,
        const unsigned short* __restrict__ value, float* __restrict__ out) {
    __shared__ unsigned lds2[32][64];   // half2 channel-pairs [ci2][p]; A->B then C->D

    const int tid = threadIdx.x;
    const int bid = swz(blockIdx.x);
    const int b = bid / (kH * (kW / 64));
    const int rem = bid % (kH * (kW / 64));
    const int h = rem / (kW / 64);
    const int w0 = (rem % (kW / 64)) * 64;

    const int p = tid & 63;
    const int gs = __builtin_amdgcn_readfirstlane(tid >> 6);   // wave-uniform -> SGPR

    // ---- stage A: depthwise 3x3 conv (zero pad) -> half2 pairs in lds2 ----
    {
        const int w = w0 + p;
        #pragma unroll 2
        for (int q = 0; q < 8; ++q) {
            float sv[2];
            #pragma unroll
            for (int e = 0; e < 2; ++e) {
                const int c = gs * 16 + 2 * q + e;          // wave-uniform
                const float* ib = inp + (size_t)(b * 64 + c) * kHW;
                float s = bdw[c];
                #pragma unroll
                for (int r = 0; r < 3; ++r) {
                    const int y = h - 1 + r;
                    if (y >= 0 && y < kH) {
                        const float* rowp = ib + (size_t)y * kW;
                        #pragma unroll
                        for (int kx = 0; kx < 3; ++kx) {
                            const int x = w - 1 + kx;
                            const float v = (x >= 0 && x < kW) ? rowp[x] : 0.f;
                            s = fmaf(v, Wdw[c * 9 + r * 3 + kx], s);
                        }
                    }
                }
                sv[e] = s;
            }
            lds2[gs * 8 + q][p] = pack2h(sv[0], sv[1]);
        }
    }
    __syncthreads();

    // ---- stage B: om[27] via v_dot2_f32_f16 (channel pairs), fp32 accum ----
    float om[27];
    {
        const float* bg = bom + gs * 27;                // scalar loads
        #pragma unroll
        for (int j = 0; j < 27; ++j) om[j] = bg[j];
        #pragma unroll 4
        for (int ci2 = 0; ci2 < 32; ++ci2) {
            const unsigned a2 = lds2[ci2][p];           // 1 ds_read_b32 / pair
            const unsigned* wr = g_Wom2 + ci2 * kOMD + gs * 27;  // wave-uniform
            #pragma unroll
            for (int j = 0; j < 27; ++j) om[j] = dot2(a2, wr[j], om[j]);
        }
    }
    __syncthreads();   // lds2 reads done; stage C will overwrite

    // ---- stage C: deformable bilinear sampling (fp16 value, v_fma_mix) ----
    {
        float acc[16];
        #pragma unroll
        for (int j = 0; j < 16; ++j) acc[j] = 0.f;
        const float fw = (float)(w0 + p);
        const float fh = (float)h;
        const unsigned short* vbase = value + (size_t)(b * 4 + gs) * kHW * 16;
        #pragma unroll
        for (int k = 0; k < 9; ++k) {
            const int ky = k / 3, kx = k % 3;
            const float dx = om[2 * k];
            const float dy = om[2 * k + 1];
            const float m = om[18 + k];
            const float px = fw + (float)(kx - 1) + dx;
            const float py = fh + (float)(ky - 1) + dy;
            const float x0f = floorf(px), y0f = floorf(py);
            const int x0 = (int)x0f, y0 = (int)y0f;
            const float wx1 = px - x0f, wy1 = py - y0f;
            const float wx0 = 1.f - wx1, wy0 = 1.f - wy1;
            #pragma unroll
            for (int cor = 0; cor < 4; ++cor) {
                const int dy2 = cor >> 1, dx2 = cor & 1;
                const int xi = x0 + dx2, yi = y0 + dy2;
                float wgt = (dy2 ? wy1 : wy0) * (dx2 ? wx1 : wx0) * m;
                if (xi < 0 || xi >= kW || yi < 0 || yi >= kH) wgt = 0.f;
                const int xc = min(max(xi, 0), kW - 1);
                const int yc = min(max(yi, 0), kH - 1);
                const uint4* vp = (const uint4*)(vbase +
                        ((size_t)yc * kW + xc) * 16);
                const uint4 u0 = vp[0];
                const uint4 u1 = vp[1];
                fma2h(acc[0],  acc[1],  wgt, u0.x);
                fma2h(acc[2],  acc[3],  wgt, u0.y);
                fma2h(acc[4],  acc[5],  wgt, u0.z);
                fma2h(acc[6],  acc[7],  wgt, u0.w);
                fma2h(acc[8],  acc[9],  wgt, u1.x);
                fma2h(acc[10], acc[11], wgt, u1.y);
                fma2h(acc[12], acc[13], wgt, u1.z);
                fma2h(acc[14], acc[15], wgt, u1.w);
            }
        }
        // write sampled result as half2 channel-pairs (dw is dead now)
        #pragma unroll
        for (int j = 0; j < 8; ++j)
            lds2[gs * 8 + j][p] = pack2h(acc[2 * j], acc[2 * j + 1]);
    }
    __syncthreads();

    // ---- stage D: final @Wo via v_dot2_f32_f16, coalesced (B,C,H,W) writeout ----
    {
        float acc[16];
        #pragma unroll
        for (int j = 0; j < 16; ++j) acc[j] = 0.f;
        #pragma unroll 4
        for (int ci2 = 0; ci2 < 32; ++ci2) {
            const unsigned a2 = lds2[ci2][p];
            const unsigned* wr = g_Wo2 + ci2 * 64 + gs * 16;   // wave-uniform
            #pragma unroll
            for (int j = 0; j < 16; ++j) acc[j] = dot2(a2, wr[j], acc[j]);
        }
        float* ob = out + (size_t)(b * 64 + gs * 16) * kHW + (size_t)h * kW + w0 + p;
        #pragma unroll
        for (int j = 0; j < 16; ++j) ob[(size_t)j * kHW] = acc[j];
    }
}

extern "C" void kernel_launch(void* const* d_in, const int* in_sizes, int n_in,
                              void* d_out, int out_size, void* d_ws, size_t ws_size,
                              hipStream_t stream) {
    const float* inp = (const float*)d_in[0];
    const float* Wv  = (const float*)d_in[1];
    const float* bv  = (const float*)d_in[2];
    const float* Wdw = (const float*)d_in[3];
    const float* bdw = (const float*)d_in[4];
    const float* Wom = (const float*)d_in[5];
    const float* bom = (const float*)d_in[6];
    const float* Wo  = (const float*)d_in[7];
    float* outp = (float*)d_out;
    unsigned short* value = (unsigned short*)d_ws;   // [b][g][yx][16] fp16 = 37.7 MB

    k_value<<<kNB, 256, 0, stream>>>(inp, Wv, bv, Wom, Wo, value);
    k_main<<<kNB, 256, 0, stream>>>(inp, Wdw, bdw, bom, value, outp);
}